// Round 9
// baseline (447.225 us; speedup 1.0000x reference)
//
#include <hip/hip_runtime.h>
#include <hip/hip_bf16.h>

// Grouped experts GEMM: out[t, o] = sum_k input[t,k] * weight[e(t), o, k] + bias[e(t), o]
// E=8, T=32768, DIN(K)=1024, DOUT(N)=4096.
//
// Round 9: occupancy-first redesign. Per-wave 64x64 (acc 64 AGPR, ~45 arch
// VGPR -> <=128 total), block tile 256x128, BK=32, 8 waves, LDS 48 KiB dbuf
// -> 2 blocks/CU, 4 waves/SIMD. Cross-block TLP hides the barrier/read-burst
// dead time that capped rounds 2-8 at ~37% MfmaUtil (2 lockstep waves/SIMD).
// Persistent 512-block walk, seamless cross-tile staging, merged cvt.

#define DEVFN __device__ __forceinline__

constexpr int E_    = 8;
constexpr int T_    = 32768;
constexpr int DIN_  = 1024;   // K
constexpr int DOUT_ = 4096;   // N

typedef __attribute__((ext_vector_type(8))) __bf16 bf16x8;   // MFMA A/B frag (4 VGPR)
typedef __attribute__((ext_vector_type(4))) float  f32x4;    // MFMA C/D frag
typedef __attribute__((ext_vector_type(8))) short  s16x8;

DEVFN unsigned short f2bf(float x) {
  unsigned u = __builtin_bit_cast(unsigned, x);
  u += 0x7fffu + ((u >> 16) & 1u);
  return (unsigned short)(u >> 16);
}

DEVFN long long expert_offset(const void* cnts, int e) {
  const int* c32 = (const int*)cnts;
  long long s = 0;
  for (int i = 0; i < E_; ++i) s += c32[i];
  if (s == (long long)T_) {
    long long o = 0;
    for (int i = 0; i < e; ++i) o += c32[i];
    return o;
  }
  const long long* c64 = (const long long*)cnts;
  long long o = 0;
  for (int i = 0; i < e; ++i) o += c64[i];
  return o;
}

// Combined f32->bf16 conversion for input (nA4 float4s) and weight (nW4).
__global__ __launch_bounds__(256) void cvt2_kernel(const float* __restrict__ ia,
                                                   const float* __restrict__ iw,
                                                   unsigned short* __restrict__ oa,
                                                   unsigned short* __restrict__ ow,
                                                   int nA4, int nW4) {
  int i = blockIdx.x * 256 + threadIdx.x;
  const float* src;
  unsigned short* dst;
  int j;
  if (i < nA4) { src = ia; dst = oa; j = i; }
  else         { j = i - nA4; if (j >= nW4) return; src = iw; dst = ow; }
  const float4 f = reinterpret_cast<const float4*>(src)[j];
  ushort4 h;
  h.x = f2bf(f.x); h.y = f2bf(f.y); h.z = f2bf(f.z); h.w = f2bf(f.w);
  reinterpret_cast<ushort4*>(dst)[j] = h;
}

// ---------------------------------------------------------------------------
// Persistent grouped GEMM: 512 blocks x 512 threads (2 blocks/CU target);
// block p -> expert e=p&7 (XCD-local), q=p>>3 in [0,64). 8 tiles per block:
//   tm = (q>>4)*4 + (it&3) in [0,16), tn = (it>>2)*16 + (q&15) in [0,32)
// Per tile: 256x128, 8 waves (4M x 2N), per-wave 64x64 = acc[4][4]. BK=32.
// LDS per buffer: A 256x32x2B = 16KB @0, B 128x32x2B = 8KB @16384; dbuf 48KB.
// Granule swizzle (4 x 16B per 64B row): c ^= (r&3), on pre-swizzled global
// source (linear LDS dest) and on the ds_read address (involution; row&3 ==
// rsel&3 since fragment row bases are multiples of 16).
// K-tile (2 barriers, 8 MFMA per region):
//   R1: read a[0..3] + b[0..3] (8 ds_read_b128); Q(nf0,nf1); lgkmcnt(0); BAR
//   R2: stage A(kt+2) (2 loads) + B(kt+2) (1 load); Q(nf2,nf3); vmcnt(3); BAR
// kt30/31 stage next tile's kt0/1 -> seamless 256-K-tile pipeline per block.
// ---------------------------------------------------------------------------
__global__ __launch_bounds__(512, 4) void gemm9_kernel(const unsigned short* __restrict__ wa,
                                                       const unsigned short* __restrict__ wb,
                                                       const float* __restrict__ bias,
                                                       const void* __restrict__ counts,
                                                       float* __restrict__ out) {
  __shared__ __align__(16) unsigned char lds[2][24576];

  const int tid  = threadIdx.x;
  const int lane = tid & 63;
  const int wid  = tid >> 6;
  const int wm = wid >> 1, wn = wid & 1;   // 4 x 2 wave grid

  const int p = blockIdx.x;
  const int e = p & 7;
  const int q = p >> 3;                    // 0..63

  const long long off = expert_offset(counts, e);
  const unsigned short* wae = wa + off * (long long)DIN_;
  const unsigned short* wbe = wb + (long long)e * DOUT_ * DIN_;
  const float* be = bias + e * DOUT_;

  // Staging source offsets (pre-swizzled global; linear LDS dest).
  int goffA[2], goffB;
#pragma unroll
  for (int rd = 0; rd < 2; ++rd) {
    const int chunk = rd * 512 + tid;      // A: 1024 granules (256 rows x 4)
    const int r = chunk >> 2, c = chunk & 3;
    goffA[rd] = r * DIN_ + ((c ^ (r & 3)) << 3);
  }
  {
    const int r = tid >> 2, c = tid & 3;   // B: 512 granules (128 rows x 4)
    goffB = r * DIN_ + ((c ^ (r & 3)) << 3);
  }
  auto stageAB = [&](const unsigned short* ga, const unsigned short* gb, unsigned char* l) {
#pragma unroll
    for (int rd = 0; rd < 2; ++rd)
      __builtin_amdgcn_global_load_lds(
          (const __attribute__((address_space(1))) void*)(ga + goffA[rd]),
          (__attribute__((address_space(3))) void*)(l + (rd * 512 + tid) * 16), 16, 0, 0);
    __builtin_amdgcn_global_load_lds(
        (const __attribute__((address_space(1))) void*)(gb + goffB),
        (__attribute__((address_space(3))) void*)(l + 16384 + tid * 16), 16, 0, 0);
  };

  // ds_read addressing: row = base + rsel, granule hi, swizzle hi^(rsel&3).
  const int rsel = lane & 15, hi = lane >> 4;
  const int swz = ((hi ^ (rsel & 3)) << 4);
  const int abyte = (wm * 64 + rsel) * 64 + swz;           // + mf*1024 imm
  const int bbyte = 16384 + (wn * 64 + rsel) * 64 + swz;   // + nf*1024 imm

  bf16x8 a[4], b[4];
  f32x4  acc[4][4];      // [mf][nf]

  int tm = q >> 4, tn = q & 15;
  tm *= 4;                                   // base; + (it&3)
  const unsigned short* wat = wae + (long long)tm * 256 * DIN_;
  const unsigned short* wbt = wbe + (long long)tn * 128 * DIN_;
  stageAB(wat,      wbt,      &lds[0][0]);
  stageAB(wat + 32, wbt + 32, &lds[1][0]);
  asm volatile("s_waitcnt vmcnt(3)" ::: "memory");   // K-tile 0 landed; 1 in flight
  __builtin_amdgcn_s_barrier();

  for (int it = 0; it < 8; ++it) {
    const int ctm = (q >> 4) * 4 + (it & 3);
    const int ctn = (it >> 2) * 16 + (q & 15);
    const int ocol0 = ctn * 128 + wn * 64;
    // Bias folded into accumulator init (epilogue becomes pure stores).
    {
      const float bv0 = be[ocol0 + rsel];
      const float bv1 = be[ocol0 + 16 + rsel];
      const float bv2 = be[ocol0 + 32 + rsel];
      const float bv3 = be[ocol0 + 48 + rsel];
#pragma unroll
      for (int mf = 0; mf < 4; ++mf) {
        acc[mf][0] = (f32x4){bv0, bv0, bv0, bv0};
        acc[mf][1] = (f32x4){bv1, bv1, bv1, bv1};
        acc[mf][2] = (f32x4){bv2, bv2, bv2, bv2};
        acc[mf][3] = (f32x4){bv3, bv3, bv3, bv3};
      }
    }
    const bool have_next = (it < 7);
    int ntm = ctm, ntn = ctn;
    if (have_next) { ntm = (q >> 4) * 4 + ((it + 1) & 3); ntn = ((it + 1) >> 2) * 16 + (q & 15); }
    const unsigned short* nat = wae + (long long)ntm * 256 * DIN_;
    const unsigned short* nbt = wbe + (long long)ntn * 128 * DIN_;

    for (int kt = 0; kt < 32; ++kt) {
      unsigned char* Lb = &lds[kt & 1][0];
      const unsigned short* pfa = nullptr;
      const unsigned short* pfb = nullptr;
      int nend = -1;
      if (kt < 30)        { pfa = wat + (kt + 2) * 32; pfb = wbt + (kt + 2) * 32; nend = 3; }
      else if (have_next) { pfa = nat + (kt - 30) * 32; pfb = nbt + (kt - 30) * 32; nend = 3; }
      else if (kt == 30)  { nend = 0; }

      // ---- R1: all 8 ds_reads + quadrants nf0, nf1.
#pragma unroll
      for (int mf = 0; mf < 4; ++mf)
        a[mf] = *(const bf16x8*)(Lb + abyte + mf * 1024);
#pragma unroll
      for (int nf = 0; nf < 4; ++nf)
        b[nf] = *(const bf16x8*)(Lb + bbyte + nf * 1024);
      __builtin_amdgcn_s_setprio(1);
#pragma unroll
      for (int nf = 0; nf < 2; ++nf)
#pragma unroll
        for (int mf = 0; mf < 4; ++mf)
          acc[mf][nf] = __builtin_amdgcn_mfma_f32_16x16x32_bf16(a[mf], b[nf], acc[mf][nf], 0, 0, 0);
      __builtin_amdgcn_s_setprio(0);
      asm volatile("s_waitcnt lgkmcnt(0)" ::: "memory");  // all reads landed in regs
      __builtin_amdgcn_s_barrier();

      // ---- R2: stage kt+2 into the just-freed buffer; quadrants nf2, nf3.
      if (pfa) stageAB(pfa, pfb, Lb);
      __builtin_amdgcn_sched_barrier(0);       // staging issues before MFMA cluster
      __builtin_amdgcn_s_setprio(1);
#pragma unroll
      for (int nf = 2; nf < 4; ++nf)
#pragma unroll
        for (int mf = 0; mf < 4; ++mf)
          acc[mf][nf] = __builtin_amdgcn_mfma_f32_16x16x32_bf16(a[mf], b[nf], acc[mf][nf], 0, 0, 0);
      __builtin_amdgcn_s_setprio(0);
      if (nend == 3)      asm volatile("s_waitcnt vmcnt(3)" ::: "memory");
      else if (nend == 0) asm volatile("s_waitcnt vmcnt(0)" ::: "memory");
      __builtin_amdgcn_s_barrier();
    }

    // Epilogue: pure stores (bias already in acc). C/D: col=lane&15,
    // row=(lane>>4)*4+j. nf innermost -> 4 consecutive 64B stores = 256B/row.
    const long long orow0 = off + (long long)ctm * 256 + wm * 64;
#pragma unroll
    for (int mf = 0; mf < 4; ++mf) {
      const int rl = mf * 16 + hi * 4;
#pragma unroll
      for (int j = 0; j < 4; ++j) {
        float* rp = out + (orow0 + rl + j) * (long long)DOUT_ + ocol0 + rsel;
        rp[0]  = acc[mf][0][j];
        rp[16] = acc[mf][1][j];
        rp[32] = acc[mf][2][j];
        rp[48] = acc[mf][3][j];
      }
    }
    wat = nat; wbt = nbt;
  }
}

// ---------------------------------------------------------------------------
// Fallback (ws too small): 128x128, reg-staged f32->bf16 (round-1 proven).
// ---------------------------------------------------------------------------
__global__ __launch_bounds__(256) void gemm_fb_kernel(const float* __restrict__ Af,
                                                      const float* __restrict__ Bf,
                                                      const float* __restrict__ bias,
                                                      const void* __restrict__ counts,
                                                      float* __restrict__ out) {
  constexpr int RS = 144;
  constexpr int BBASE = 128 * RS;
  __shared__ __align__(16) unsigned char lds[2 * 128 * RS];

  const int tid  = threadIdx.x;
  const int lane = tid & 63;
  const int wid  = tid >> 6;
  const int wm = wid >> 1, wn = wid & 1;

  const int bid = blockIdx.x;
  const int e  = bid >> 10;
  const int t  = bid & 1023;
  const int tm = t >> 5, tn = t & 31;

  const long long off = expert_offset(counts, e);
  const long long rowA0 = off + (long long)tm * 128;
  const int n0 = tn * 128;

  f32x4 acc[4][4] = {};

  for (int kt = 0; kt < DIN_ / 64; ++kt) {
    const int k0 = kt * 64;
#pragma unroll
    for (int rd = 0; rd < 8; ++rd) {
      const int chunk = rd * 256 + tid;
      const int c2 = chunk & 1023;
      const int r  = c2 >> 3;
      const int c  = c2 & 7;
      const float* src =
          (rd < 4) ? (Af + (rowA0 + r) * (long long)DIN_ + (k0 + c * 8))
                   : (Bf + ((long long)(e * DOUT_ + n0 + r)) * DIN_ + (k0 + c * 8));
      const float4 f0 = *reinterpret_cast<const float4*>(src);
      const float4 f1 = *reinterpret_cast<const float4*>(src + 4);
      s16x8 v;
      v[0] = (short)f2bf(f0.x); v[1] = (short)f2bf(f0.y);
      v[2] = (short)f2bf(f0.z); v[3] = (short)f2bf(f0.w);
      v[4] = (short)f2bf(f1.x); v[5] = (short)f2bf(f1.y);
      v[6] = (short)f2bf(f1.z); v[7] = (short)f2bf(f1.w);
      *reinterpret_cast<s16x8*>(&lds[((rd < 4) ? 0 : BBASE) + r * RS + (c << 4)]) = v;
    }
    __syncthreads();
#pragma unroll
    for (int kk = 0; kk < 2; ++kk) {
      const int rs = lane & 15;
      const int cs = kk * 4 + (lane >> 4);
      bf16x8 af[4], bfr[4];
#pragma unroll
      for (int mf = 0; mf < 4; ++mf)
        af[mf] = *reinterpret_cast<const bf16x8*>(&lds[(wm * 64 + mf * 16 + rs) * RS + (cs << 4)]);
#pragma unroll
      for (int nf = 0; nf < 4; ++nf)
        bfr[nf] = *reinterpret_cast<const bf16x8*>(&lds[BBASE + (wn * 64 + nf * 16 + rs) * RS + (cs << 4)]);
#pragma unroll
      for (int mf = 0; mf < 4; ++mf)
#pragma unroll
        for (int nf = 0; nf < 4; ++nf)
          acc[mf][nf] = __builtin_amdgcn_mfma_f32_16x16x32_bf16(af[mf], bfr[nf], acc[mf][nf], 0, 0, 0);
    }
    __syncthreads();
  }

  const long long orow0 = off + (long long)tm * 128 + wm * 64;
  const int ocol0 = n0 + wn * 64;
  const int rlo = (lane >> 4) * 4;
  const int c15 = lane & 15;
#pragma unroll
  for (int nf = 0; nf < 4; ++nf) {
    const int n = ocol0 + nf * 16 + c15;
    const float bv = bias[e * DOUT_ + n];
#pragma unroll
    for (int mf = 0; mf < 4; ++mf) {
      const long long mrow = orow0 + mf * 16 + rlo;
#pragma unroll
      for (int j = 0; j < 4; ++j)
        out[(mrow + j) * (long long)DOUT_ + n] = acc[mf][nf][j] + bv;
    }
  }
}

extern "C" void kernel_launch(void* const* d_in, const int* in_sizes, int n_in,
                              void* d_out, int out_size, void* d_ws, size_t ws_size,
                              hipStream_t stream) {
  const float* input  = (const float*)d_in[0];
  const float* weight = (const float*)d_in[1];
  const float* bias   = (const float*)d_in[2];
  const void*  counts = (const void*)d_in[3];
  float* out = (float*)d_out;

  const size_t nA = (size_t)T_ * DIN_;
  const size_t nW = (size_t)E_ * DOUT_ * DIN_;
  const size_t need = (nA + nW) * sizeof(unsigned short);

  if (ws_size >= need) {
    unsigned short* wa = (unsigned short*)d_ws;
    unsigned short* wb = wa + nA;
    const int nA4 = (int)(nA / 4), nW4 = (int)(nW / 4);
    cvt2_kernel<<<dim3((unsigned)((nA4 + nW4) / 256)), dim3(256), 0, stream>>>(
        input, weight, wa, wb, nA4, nW4);
    gemm9_kernel<<<dim3(512), dim3(512), 0, stream>>>(wa, wb, bias, counts, out);
  } else {
    gemm_fb_kernel<<<dim3(E_ * 32 * 32), dim3(256), 0, stream>>>(input, weight, bias, counts, out);
  }
}

// Round 10
// 443.560 us; speedup vs baseline: 1.0083x; 1.0083x over previous
//
#include <hip/hip_runtime.h>
#include <hip/hip_bf16.h>

// Grouped experts GEMM: out[t, o] = sum_k input[t,k] * weight[e(t), o, k] + bias[e(t), o]
// E=8, T=32768, DIN(K)=1024, DOUT(N)=4096.
//
// Round 10: round-9 occupancy structure (64x64/wave, 256x128 tile, BK=32,
// 48 KiB LDS -> 2 blocks/CU, 4 waves/SIMD) with the BANK-CONFLICT FIX:
// swizzle g = hi ^ ((row>>1)&3) (round-3-proven for 64B rows) instead of
// r9's g = hi ^ (row&3) which 4-way-conflicted (3.35e7 conflict cycles).
// Applied consistently to the pre-swizzled global staging source and the
// ds_read address (same involution on both sides).

#define DEVFN __device__ __forceinline__

constexpr int E_    = 8;
constexpr int T_    = 32768;
constexpr int DIN_  = 1024;   // K
constexpr int DOUT_ = 4096;   // N

typedef __attribute__((ext_vector_type(8))) __bf16 bf16x8;   // MFMA A/B frag (4 VGPR)
typedef __attribute__((ext_vector_type(4))) float  f32x4;    // MFMA C/D frag
typedef __attribute__((ext_vector_type(8))) short  s16x8;

DEVFN unsigned short f2bf(float x) {
  unsigned u = __builtin_bit_cast(unsigned, x);
  u += 0x7fffu + ((u >> 16) & 1u);
  return (unsigned short)(u >> 16);
}

DEVFN long long expert_offset(const void* cnts, int e) {
  const int* c32 = (const int*)cnts;
  long long s = 0;
  for (int i = 0; i < E_; ++i) s += c32[i];
  if (s == (long long)T_) {
    long long o = 0;
    for (int i = 0; i < e; ++i) o += c32[i];
    return o;
  }
  const long long* c64 = (const long long*)cnts;
  long long o = 0;
  for (int i = 0; i < e; ++i) o += c64[i];
  return o;
}

// Combined f32->bf16 conversion for input (nA4 float4s) and weight (nW4).
__global__ __launch_bounds__(256) void cvt2_kernel(const float* __restrict__ ia,
                                                   const float* __restrict__ iw,
                                                   unsigned short* __restrict__ oa,
                                                   unsigned short* __restrict__ ow,
                                                   int nA4, int nW4) {
  int i = blockIdx.x * 256 + threadIdx.x;
  const float* src;
  unsigned short* dst;
  int j;
  if (i < nA4) { src = ia; dst = oa; j = i; }
  else         { j = i - nA4; if (j >= nW4) return; src = iw; dst = ow; }
  const float4 f = reinterpret_cast<const float4*>(src)[j];
  ushort4 h;
  h.x = f2bf(f.x); h.y = f2bf(f.y); h.z = f2bf(f.z); h.w = f2bf(f.w);
  reinterpret_cast<ushort4*>(dst)[j] = h;
}

// ---------------------------------------------------------------------------
// Persistent grouped GEMM: 512 blocks x 512 threads (2 blocks/CU);
// block p -> expert e=p&7 (XCD-local), q=p>>3 in [0,64). 8 tiles per block:
//   tm = (q>>4)*4 + (it&3) in [0,16), tn = (it>>2)*16 + (q&15) in [0,32)
// Per tile: 256x128, 8 waves (4M x 2N), per-wave 64x64 = acc[4][4]. BK=32.
// LDS per buffer: A 16KB @0, B 8KB @16384; dbuf 48KB.
// Granule swizzle (4 x 16B per 64B row): g ^= (row>>1)&3 -- conflict-free
// (bank starts {0,16,4,20,8,24,12,28} across row&7, 2 lanes/bank = free).
// K-tile (2 barriers, 8 MFMA per region):
//   R1: read a[0..3] + b[0..3] (8 ds_read_b128); Q(nf0,nf1); lgkmcnt(0); BAR
//   R2: stage A(kt+2) (2 loads) + B(kt+2) (1 load); Q(nf2,nf3); vmcnt(3); BAR
// kt30/31 stage next tile's kt0/1 -> seamless 256-K-tile pipeline per block.
// ---------------------------------------------------------------------------
__global__ __launch_bounds__(512, 4) void gemm10_kernel(const unsigned short* __restrict__ wa,
                                                        const unsigned short* __restrict__ wb,
                                                        const float* __restrict__ bias,
                                                        const void* __restrict__ counts,
                                                        float* __restrict__ out) {
  __shared__ __align__(16) unsigned char lds[2][24576];

  const int tid  = threadIdx.x;
  const int lane = tid & 63;
  const int wid  = tid >> 6;
  const int wm = wid >> 1, wn = wid & 1;   // 4 x 2 wave grid

  const int p = blockIdx.x;
  const int e = p & 7;
  const int q = p >> 3;                    // 0..63

  const long long off = expert_offset(counts, e);
  const unsigned short* wae = wa + off * (long long)DIN_;
  const unsigned short* wbe = wb + (long long)e * DOUT_ * DIN_;
  const float* be = bias + e * DOUT_;

  // Staging source offsets (pre-swizzled global; linear LDS dest).
  // Involution: LDS slot c holds global granule c ^ ((r>>1)&3).
  int goffA[2], goffB;
#pragma unroll
  for (int rd = 0; rd < 2; ++rd) {
    const int chunk = rd * 512 + tid;      // A: 1024 granules (256 rows x 4)
    const int r = chunk >> 2, c = chunk & 3;
    goffA[rd] = r * DIN_ + ((c ^ ((r >> 1) & 3)) << 3);
  }
  {
    const int r = tid >> 2, c = tid & 3;   // B: 512 granules (128 rows x 4)
    goffB = r * DIN_ + ((c ^ ((r >> 1) & 3)) << 3);
  }
  auto stageAB = [&](const unsigned short* ga, const unsigned short* gb, unsigned char* l) {
#pragma unroll
    for (int rd = 0; rd < 2; ++rd)
      __builtin_amdgcn_global_load_lds(
          (const __attribute__((address_space(1))) void*)(ga + goffA[rd]),
          (__attribute__((address_space(3))) void*)(l + (rd * 512 + tid) * 16), 16, 0, 0);
    __builtin_amdgcn_global_load_lds(
        (const __attribute__((address_space(1))) void*)(gb + goffB),
        (__attribute__((address_space(3))) void*)(l + 16384 + tid * 16), 16, 0, 0);
  };

  // ds_read addressing: row = base + rsel (base % 16 == 0), granule hi,
  // slot = hi ^ ((row>>1)&3) = hi ^ ((rsel>>1)&3) -- lane-constant.
  const int rsel = lane & 15, hi = lane >> 4;
  const int swz = ((hi ^ ((rsel >> 1) & 3)) << 4);
  const int abyte = (wm * 64 + rsel) * 64 + swz;           // + mf*1024 imm
  const int bbyte = 16384 + (wn * 64 + rsel) * 64 + swz;   // + nf*1024 imm

  bf16x8 a[4], b[4];
  f32x4  acc[4][4];      // [mf][nf]

  int tm = q >> 4, tn = q & 15;
  tm *= 4;                                   // base; + (it&3)
  const unsigned short* wat = wae + (long long)tm * 256 * DIN_;
  const unsigned short* wbt = wbe + (long long)tn * 128 * DIN_;
  stageAB(wat,      wbt,      &lds[0][0]);
  stageAB(wat + 32, wbt + 32, &lds[1][0]);
  asm volatile("s_waitcnt vmcnt(3)" ::: "memory");   // K-tile 0 landed; 1 in flight
  __builtin_amdgcn_s_barrier();

  for (int it = 0; it < 8; ++it) {
    const int ctm = (q >> 4) * 4 + (it & 3);
    const int ctn = (it >> 2) * 16 + (q & 15);
    const int ocol0 = ctn * 128 + wn * 64;
    // Bias folded into accumulator init (epilogue becomes pure stores).
    {
      const float bv0 = be[ocol0 + rsel];
      const float bv1 = be[ocol0 + 16 + rsel];
      const float bv2 = be[ocol0 + 32 + rsel];
      const float bv3 = be[ocol0 + 48 + rsel];
#pragma unroll
      for (int mf = 0; mf < 4; ++mf) {
        acc[mf][0] = (f32x4){bv0, bv0, bv0, bv0};
        acc[mf][1] = (f32x4){bv1, bv1, bv1, bv1};
        acc[mf][2] = (f32x4){bv2, bv2, bv2, bv2};
        acc[mf][3] = (f32x4){bv3, bv3, bv3, bv3};
      }
    }
    const bool have_next = (it < 7);
    int ntm = ctm, ntn = ctn;
    if (have_next) { ntm = (q >> 4) * 4 + ((it + 1) & 3); ntn = ((it + 1) >> 2) * 16 + (q & 15); }
    const unsigned short* nat = wae + (long long)ntm * 256 * DIN_;
    const unsigned short* nbt = wbe + (long long)ntn * 128 * DIN_;

    for (int kt = 0; kt < 32; ++kt) {
      unsigned char* Lb = &lds[kt & 1][0];
      const unsigned short* pfa = nullptr;
      const unsigned short* pfb = nullptr;
      int nend = -1;
      if (kt < 30)        { pfa = wat + (kt + 2) * 32; pfb = wbt + (kt + 2) * 32; nend = 3; }
      else if (have_next) { pfa = nat + (kt - 30) * 32; pfb = nbt + (kt - 30) * 32; nend = 3; }
      else if (kt == 30)  { nend = 0; }

      // ---- R1: all 8 ds_reads + quadrants nf0, nf1.
#pragma unroll
      for (int mf = 0; mf < 4; ++mf)
        a[mf] = *(const bf16x8*)(Lb + abyte + mf * 1024);
#pragma unroll
      for (int nf = 0; nf < 4; ++nf)
        b[nf] = *(const bf16x8*)(Lb + bbyte + nf * 1024);
      __builtin_amdgcn_s_setprio(1);
#pragma unroll
      for (int nf = 0; nf < 2; ++nf)
#pragma unroll
        for (int mf = 0; mf < 4; ++mf)
          acc[mf][nf] = __builtin_amdgcn_mfma_f32_16x16x32_bf16(a[mf], b[nf], acc[mf][nf], 0, 0, 0);
      __builtin_amdgcn_s_setprio(0);
      asm volatile("s_waitcnt lgkmcnt(0)" ::: "memory");  // all reads landed in regs
      __builtin_amdgcn_s_barrier();

      // ---- R2: stage kt+2 into the just-freed buffer; quadrants nf2, nf3.
      if (pfa) stageAB(pfa, pfb, Lb);
      __builtin_amdgcn_sched_barrier(0);       // staging issues before MFMA cluster
      __builtin_amdgcn_s_setprio(1);
#pragma unroll
      for (int nf = 2; nf < 4; ++nf)
#pragma unroll
        for (int mf = 0; mf < 4; ++mf)
          acc[mf][nf] = __builtin_amdgcn_mfma_f32_16x16x32_bf16(a[mf], b[nf], acc[mf][nf], 0, 0, 0);
      __builtin_amdgcn_s_setprio(0);
      if (nend == 3)      asm volatile("s_waitcnt vmcnt(3)" ::: "memory");
      else if (nend == 0) asm volatile("s_waitcnt vmcnt(0)" ::: "memory");
      __builtin_amdgcn_s_barrier();
    }

    // Epilogue: pure stores (bias already in acc). C/D: col=lane&15,
    // row=(lane>>4)*4+j. nf innermost -> 4 consecutive 64B stores = 256B/row.
    const long long orow0 = off + (long long)ctm * 256 + wm * 64;
#pragma unroll
    for (int mf = 0; mf < 4; ++mf) {
      const int rl = mf * 16 + hi * 4;
#pragma unroll
      for (int j = 0; j < 4; ++j) {
        float* rp = out + (orow0 + rl + j) * (long long)DOUT_ + ocol0 + rsel;
        rp[0]  = acc[mf][0][j];
        rp[16] = acc[mf][1][j];
        rp[32] = acc[mf][2][j];
        rp[48] = acc[mf][3][j];
      }
    }
    wat = nat; wbt = nbt;
  }
}

// ---------------------------------------------------------------------------
// Fallback (ws too small): 128x128, reg-staged f32->bf16 (round-1 proven).
// ---------------------------------------------------------------------------
__global__ __launch_bounds__(256) void gemm_fb_kernel(const float* __restrict__ Af,
                                                      const float* __restrict__ Bf,
                                                      const float* __restrict__ bias,
                                                      const void* __restrict__ counts,
                                                      float* __restrict__ out) {
  constexpr int RS = 144;
  constexpr int BBASE = 128 * RS;
  __shared__ __align__(16) unsigned char lds[2 * 128 * RS];

  const int tid  = threadIdx.x;
  const int lane = tid & 63;
  const int wid  = tid >> 6;
  const int wm = wid >> 1, wn = wid & 1;

  const int bid = blockIdx.x;
  const int e  = bid >> 10;
  const int t  = bid & 1023;
  const int tm = t >> 5, tn = t & 31;

  const long long off = expert_offset(counts, e);
  const long long rowA0 = off + (long long)tm * 128;
  const int n0 = tn * 128;

  f32x4 acc[4][4] = {};

  for (int kt = 0; kt < DIN_ / 64; ++kt) {
    const int k0 = kt * 64;
#pragma unroll
    for (int rd = 0; rd < 8; ++rd) {
      const int chunk = rd * 256 + tid;
      const int c2 = chunk & 1023;
      const int r  = c2 >> 3;
      const int c  = c2 & 7;
      const float* src =
          (rd < 4) ? (Af + (rowA0 + r) * (long long)DIN_ + (k0 + c * 8))
                   : (Bf + ((long long)(e * DOUT_ + n0 + r)) * DIN_ + (k0 + c * 8));
      const float4 f0 = *reinterpret_cast<const float4*>(src);
      const float4 f1 = *reinterpret_cast<const float4*>(src + 4);
      s16x8 v;
      v[0] = (short)f2bf(f0.x); v[1] = (short)f2bf(f0.y);
      v[2] = (short)f2bf(f0.z); v[3] = (short)f2bf(f0.w);
      v[4] = (short)f2bf(f1.x); v[5] = (short)f2bf(f1.y);
      v[6] = (short)f2bf(f1.z); v[7] = (short)f2bf(f1.w);
      *reinterpret_cast<s16x8*>(&lds[((rd < 4) ? 0 : BBASE) + r * RS + (c << 4)]) = v;
    }
    __syncthreads();
#pragma unroll
    for (int kk = 0; kk < 2; ++kk) {
      const int rs = lane & 15;
      const int cs = kk * 4 + (lane >> 4);
      bf16x8 af[4], bfr[4];
#pragma unroll
      for (int mf = 0; mf < 4; ++mf)
        af[mf] = *reinterpret_cast<const bf16x8*>(&lds[(wm * 64 + mf * 16 + rs) * RS + (cs << 4)]);
#pragma unroll
      for (int nf = 0; nf < 4; ++nf)
        bfr[nf] = *reinterpret_cast<const bf16x8*>(&lds[BBASE + (wn * 64 + nf * 16 + rs) * RS + (cs << 4)]);
#pragma unroll
      for (int mf = 0; mf < 4; ++mf)
#pragma unroll
        for (int nf = 0; nf < 4; ++nf)
          acc[mf][nf] = __builtin_amdgcn_mfma_f32_16x16x32_bf16(af[mf], bfr[nf], acc[mf][nf], 0, 0, 0);
    }
    __syncthreads();
  }

  const long long orow0 = off + (long long)tm * 128 + wm * 64;
  const int ocol0 = n0 + wn * 64;
  const int rlo = (lane >> 4) * 4;
  const int c15 = lane & 15;
#pragma unroll
  for (int nf = 0; nf < 4; ++nf) {
    const int n = ocol0 + nf * 16 + c15;
    const float bv = bias[e * DOUT_ + n];
#pragma unroll
    for (int mf = 0; mf < 4; ++mf) {
      const long long mrow = orow0 + mf * 16 + rlo;
#pragma unroll
      for (int j = 0; j < 4; ++j)
        out[(mrow + j) * (long long)DOUT_ + n] = acc[mf][nf][j] + bv;
    }
  }
}

extern "C" void kernel_launch(void* const* d_in, const int* in_sizes, int n_in,
                              void* d_out, int out_size, void* d_ws, size_t ws_size,
                              hipStream_t stream) {
  const float* input  = (const float*)d_in[0];
  const float* weight = (const float*)d_in[1];
  const float* bias   = (const float*)d_in[2];
  const void*  counts = (const void*)d_in[3];
  float* out = (float*)d_out;

  const size_t nA = (size_t)T_ * DIN_;
  const size_t nW = (size_t)E_ * DOUT_ * DIN_;
  const size_t need = (nA + nW) * sizeof(unsigned short);

  if (ws_size >= need) {
    unsigned short* wa = (unsigned short*)d_ws;
    unsigned short* wb = wa + nA;
    const int nA4 = (int)(nA / 4), nW4 = (int)(nW / 4);
    cvt2_kernel<<<dim3((unsigned)((nA4 + nW4) / 256)), dim3(256), 0, stream>>>(
        input, weight, wa, wb, nA4, nW4);
    gemm10_kernel<<<dim3(512), dim3(512), 0, stream>>>(wa, wb, bias, counts, out);
  } else {
    gemm_fb_kernel<<<dim3(E_ * 32 * 32), dim3(256), 0, stream>>>(input, weight, bias, counts, out);
  }
}